// Round 1
// baseline (381.866 us; speedup 1.0000x reference)
//
#include <hip/hip_runtime.h>

// Problem constants
#define B_   64
#define L_   1024
#define H_   512
#define T_   100
#define C_   97
#define TP_  112   // T (and C) padded to 7*16

typedef _Float16 h8 __attribute__((ext_vector_type(8)));   // 8 fp16 (4 VGPRs)
typedef __attribute__((ext_vector_type(4))) float f32x4;   // MFMA C/D

// ---------------------------------------------------------------------------
// k0: prep. pos_emb fp32 -> fp16 [112][512] (rows 100..111 zero);
//     W_gen fp32 -> fp16 [112][512] (rows 97..111 zero). Grid 224.
// ---------------------------------------------------------------------------
__global__ __launch_bounds__(256) void k0_prep(
    const float* __restrict__ emb, const float* __restrict__ W,
    _Float16* __restrict__ embh, _Float16* __restrict__ Wh) {
  const int row = blockIdx.x, tid = threadIdx.x;
  if (row < TP_) {
    for (int j = tid; j < H_; j += 256)
      embh[(size_t)row * H_ + j] =
          (row < T_) ? (_Float16)emb[(size_t)row * H_ + j] : (_Float16)0.f;
  } else {
    const int c = row - TP_;
    for (int j = tid; j < H_; j += 256)
      Wh[(size_t)c * H_ + j] =
          (c < C_) ? (_Float16)W[(size_t)c * H_ + j] : (_Float16)0.f;
  }
}

// ---------------------------------------------------------------------------
// K1: scores = fmap @ emb^T, f16 MFMA.
// Grid 1024 (= B*L/64), block 256: each wave owns ONE 16-row m-tile
// (64 rows/block -> 4 blocks/CU -> 16 waves/CU, vs 2 blocks/CU before).
// Stores sc[row][t] = fp16(s - M_slab) and per-64-row-slab stats (M, S)
// in part[1024][112][2].
// ---------------------------------------------------------------------------
__global__ __launch_bounds__(256) void k1_scores(
    const float* __restrict__ fmap, const _Float16* __restrict__ embh,
    _Float16* __restrict__ sc, float* __restrict__ part) {
  __shared__ float red_m[4 * TP_];
  __shared__ float red_s[4 * TP_];
  __shared__ float sMb[TP_];
  const int tid = threadIdx.x;
  const int wave = tid >> 6, lane = tid & 63;
  const int quad = lane >> 4, cc = lane & 15;
  const int m0 = blockIdx.x * 64 + wave * 16;

  f32x4 acc[7];
#pragma unroll
  for (int i = 0; i < 7; ++i) acc[i] = (f32x4){0.f, 0.f, 0.f, 0.f};

  const float* ap = fmap + (size_t)(m0 + cc) * H_ + quad * 8;
#pragma unroll 2
  for (int k = 0; k < H_; k += 32) {
    float4 x0 = *(const float4*)(ap + k);
    float4 x1 = *(const float4*)(ap + k + 4);
    h8 a;
    a[0] = (_Float16)x0.x; a[1] = (_Float16)x0.y;
    a[2] = (_Float16)x0.z; a[3] = (_Float16)x0.w;
    a[4] = (_Float16)x1.x; a[5] = (_Float16)x1.y;
    a[6] = (_Float16)x1.z; a[7] = (_Float16)x1.w;
#pragma unroll
    for (int i = 0; i < 7; ++i) {
      h8 bf = *(const h8*)(embh + (size_t)(i * 16 + cc) * H_ + k + quad * 8);
      acc[i] = __builtin_amdgcn_mfma_f32_16x16x32_f16(a, bf, acc[i], 0, 0, 0);
    }
  }

  // per-t partial softmax stats over this wave's 16 rows
  float pm[7], ps[7];
#pragma unroll
  for (int i = 0; i < 7; ++i) {
    float m = fmaxf(fmaxf(acc[i][0], acc[i][1]), fmaxf(acc[i][2], acc[i][3]));
    float s = 0.f;
#pragma unroll
    for (int r = 0; r < 4; ++r) s += __expf(acc[i][r] - m);
    pm[i] = m; ps[i] = s;
  }
#pragma unroll
  for (int d = 16; d < 64; d <<= 1) {
#pragma unroll
    for (int i = 0; i < 7; ++i) {
      float om = __shfl_xor(pm[i], d, 64);
      float os = __shfl_xor(ps[i], d, 64);
      float M = fmaxf(pm[i], om);
      ps[i] = ps[i] * __expf(pm[i] - M) + os * __expf(om - M);
      pm[i] = M;
    }
  }
  if (lane < 16) {
#pragma unroll
    for (int i = 0; i < 7; ++i) {
      red_m[wave * TP_ + i * 16 + lane] = pm[i];
      red_s[wave * TP_ + i * 16 + lane] = ps[i];
    }
  }
  __syncthreads();
  if (tid < TP_) {
    float M = red_m[tid], S = red_s[tid];
#pragma unroll
    for (int w = 1; w < 4; ++w) {
      float om = red_m[w * TP_ + tid], os = red_s[w * TP_ + tid];
      float nM = fmaxf(M, om);
      S = S * __expf(M - nM) + os * __expf(om - nM);
      M = nM;
    }
    float* p = part + ((size_t)blockIdx.x * TP_ + tid) * 2;
    p[0] = M; p[1] = S;
    sMb[tid] = M;
  }
  __syncthreads();
#pragma unroll
  for (int i = 0; i < 7; ++i) {
    float mb = sMb[i * 16 + cc];
#pragma unroll
    for (int r = 0; r < 4; ++r)
      sc[(size_t)(m0 + quad * 4 + r) * TP_ + i * 16 + cc] =
          (_Float16)(acc[i][r] - mb);
  }
}

// ---------------------------------------------------------------------------
// K2: G[b][l][c] = sum_h origin[b][l][h] * W[c][h]  (fp16 out, [65536][112])
// Reassociation: out = P^T @ (origin @ W^T). This replaces the latency-bound
// attn^T@origin GEMM with a perfectly-coalesced float4-stream GEMM identical
// in structure to K1. Grid 1024, block 256, one 16-row m-tile per wave.
// ---------------------------------------------------------------------------
__global__ __launch_bounds__(256) void k2_gmat(
    const float* __restrict__ origin, const _Float16* __restrict__ Wh,
    _Float16* __restrict__ G) {
  const int tid = threadIdx.x;
  const int wave = tid >> 6, lane = tid & 63;
  const int quad = lane >> 4, cc = lane & 15;
  const int m0 = blockIdx.x * 64 + wave * 16;

  f32x4 acc[7];
#pragma unroll
  for (int i = 0; i < 7; ++i) acc[i] = (f32x4){0.f, 0.f, 0.f, 0.f};

  const float* ap = origin + (size_t)(m0 + cc) * H_ + quad * 8;
#pragma unroll 2
  for (int k = 0; k < H_; k += 32) {
    float4 x0 = *(const float4*)(ap + k);
    float4 x1 = *(const float4*)(ap + k + 4);
    h8 a;
    a[0] = (_Float16)x0.x; a[1] = (_Float16)x0.y;
    a[2] = (_Float16)x0.z; a[3] = (_Float16)x0.w;
    a[4] = (_Float16)x1.x; a[5] = (_Float16)x1.y;
    a[6] = (_Float16)x1.z; a[7] = (_Float16)x1.w;
#pragma unroll
    for (int i = 0; i < 7; ++i) {
      h8 bf = *(const h8*)(Wh + (size_t)(i * 16 + cc) * H_ + k + quad * 8);
      acc[i] = __builtin_amdgcn_mfma_f32_16x16x32_f16(a, bf, acc[i], 0, 0, 0);
    }
  }
#pragma unroll
  for (int i = 0; i < 7; ++i)
#pragma unroll
    for (int r = 0; r < 4; ++r)
      G[(size_t)(m0 + quad * 4 + r) * TP_ + i * 16 + cc] =
          (_Float16)acc[i][r];
}

// ---------------------------------------------------------------------------
// K3: fused softmax + out[b][t][c] = sum_l P[l][t] * G[l][c] + bias[c].
// P applied on the fly: P = exp(sc + (M_slab - M_glob)) / S_glob — each sc
// element is exp'd exactly once globally (no attn materialization, no k2/k4).
// Grid 896 (= B x 7 t-tiles x 2 c-groups), block 512 (8 waves). Waves split
// the K=1024 reduction 8x128; cross-wave reduce through LDS; direct final
// write with bias. All operand data (sc, G) is L2/L3-resident.
// ---------------------------------------------------------------------------
__global__ __launch_bounds__(512) void k3_fused(
    const _Float16* __restrict__ sc, const _Float16* __restrict__ G,
    const float* __restrict__ part, const float* __restrict__ bias,
    float* __restrict__ out) {
  __shared__ float sAdj[16][16];   // [slab][t_local]
  __shared__ float sInv[16];
  __shared__ f32x4 sred[8][4][64]; // 32 KB cross-wave reduce
  const int bid = blockIdx.x;
  const int b = bid / 14;
  const int rem = bid % 14;
  const int mt = rem >> 1;              // t-tile 0..6
  const int ng = rem & 1;               // c-group: 0 -> tiles 0..3, 1 -> 4..6
  const int NT = ng ? 3 : 4;
  const int ncol0 = ng * 64;
  const int tid = threadIdx.x;
  const int w = tid >> 6, lane = tid & 63;
  const int quad = lane >> 4, cc = lane & 15;

  // merge the 16 per-slab stats of this batch for this m-tile's 16 t-columns
  if (tid < 16) {
    const int t = mt * 16 + tid;
    float mM[16];
    float M = -1e30f, S = 0.f;
#pragma unroll
    for (int s = 0; s < 16; ++s) {
      const float* p = part + ((size_t)(b * 16 + s) * TP_ + t) * 2;
      float om = p[0], os = p[1];
      mM[s] = om;
      float nM = fmaxf(M, om);
      S = S * __expf(M - nM) + os * __expf(om - nM);
      M = nM;
    }
    sInv[tid] = 1.f / S;
#pragma unroll
    for (int s = 0; s < 16; ++s) sAdj[s][tid] = mM[s] - M;
  }
  __syncthreads();

  f32x4 acc[4];
#pragma unroll
  for (int i = 0; i < 4; ++i) acc[i] = (f32x4){0.f, 0.f, 0.f, 0.f};

  const float inv = sInv[cc];
  const _Float16* scp = sc + (size_t)b * L_ * TP_ + mt * 16 + cc;
  const _Float16* gp  = G  + (size_t)b * L_ * TP_ + ncol0 + cc;
  const int kbase = w * 128;
#pragma unroll 2
  for (int l0 = kbase; l0 < kbase + 128; l0 += 32) {
    const int r0 = l0 + quad * 8;        // 8 consecutive l's stay in one slab
    const float adj = sAdj[r0 >> 6][cc];
    h8 a;
#pragma unroll
    for (int j = 0; j < 8; ++j) {
      float sv = (float)scp[(size_t)(r0 + j) * TP_];
      a[j] = (_Float16)(__expf(sv + adj) * inv);
    }
#pragma unroll
    for (int nt = 0; nt < 4; ++nt) {
      if (nt < NT) {
        h8 bf;
#pragma unroll
        for (int j = 0; j < 8; ++j)
          bf[j] = gp[(size_t)(r0 + j) * TP_ + nt * 16];
        acc[nt] = __builtin_amdgcn_mfma_f32_16x16x32_f16(a, bf, acc[nt], 0, 0, 0);
      }
    }
  }

#pragma unroll
  for (int nt = 0; nt < 4; ++nt)
    if (nt < NT) sred[w][nt][lane] = acc[nt];
  __syncthreads();

  if (w < NT) {
    f32x4 s = sred[0][w][lane];
#pragma unroll
    for (int ww = 1; ww < 8; ++ww) s += sred[ww][w][lane];
    const int c = ncol0 + w * 16 + cc;
    if (c < C_) {
      const float bv = bias[c];
#pragma unroll
      for (int r = 0; r < 4; ++r) {
        const int t = mt * 16 + quad * 4 + r;
        if (t < T_) out[((size_t)b * T_ + t) * C_ + c] = s[r] + bv;
      }
    }
  }
}

// ---------------------------------------------------------------------------
extern "C" void kernel_launch(void* const* d_in, const int* in_sizes, int n_in,
                              void* d_out, int out_size, void* d_ws, size_t ws_size,
                              hipStream_t stream) {
  const float* fmap   = (const float*)d_in[0];  // [B,L,H] fp32
  const float* origin = (const float*)d_in[1];  // [B,L,H] fp32
  const float* emb    = (const float*)d_in[2];  // [T,H]   fp32
  const float* W      = (const float*)d_in[3];  // [C,H]   fp32
  const float* bias   = (const float*)d_in[4];  // [C]     fp32
  float* out = (float*)d_out;                   // [B,T,C] fp32

  char* ws = (char*)d_ws;
  // embh f16 [112][512]        :    114,688 B @ 0
  // Wh   f16 [112][512]        :    114,688 B @ 114,688
  // sc   f16 [65536][112]      : 14,680,064 B @ 229,376
  // part f32 [1024][112][2]    :    917,504 B @ 14,909,440
  // G    f16 [65536][112]      : 14,680,064 B @ 15,826,944   (end 30.5 MB)
  _Float16* embh = (_Float16*)(ws);
  _Float16* Wh   = (_Float16*)(ws + 114688);
  _Float16* sc   = (_Float16*)(ws + 229376);
  float*    part = (float*)   (ws + 14909440);
  _Float16* G    = (_Float16*)(ws + 15826944);

  hipLaunchKernelGGL(k0_prep,   dim3(224),  dim3(256), 0, stream, emb, W, embh, Wh);
  hipLaunchKernelGGL(k1_scores, dim3(1024), dim3(256), 0, stream, fmap, embh, sc, part);
  hipLaunchKernelGGL(k2_gmat,   dim3(1024), dim3(256), 0, stream, origin, Wh, G);
  hipLaunchKernelGGL(k3_fused,  dim3(896),  dim3(512), 0, stream, sc, G, part, bias, out);
}

// Round 2
// 357.657 us; speedup vs baseline: 1.0677x; 1.0677x over previous
//
#include <hip/hip_runtime.h>

// Problem constants
#define B_   64
#define L_   1024
#define H_   512
#define T_   100
#define C_   97
#define TP_  112   // T (and C) padded to 7*16

typedef _Float16 h8 __attribute__((ext_vector_type(8)));   // 8 fp16 (4 VGPRs)
typedef __attribute__((ext_vector_type(4))) float f32x4;   // MFMA C/D

// ---------------------------------------------------------------------------
// k0: prep. pos_emb / W_gen fp32 -> fp16 in k-major-chunk layout
// E2[k/8][112][8]: element (t, k) at ((k>>3)*112 + t)*8 + (k&7).
// Rows t>=100 (emb) / c>=97 (W) are zero. Grid 224.
// This layout makes all 7 A-fragment loads per k-step immediate offsets
// (i*256 B) off a single pointer.
// ---------------------------------------------------------------------------
__global__ __launch_bounds__(256) void k0_prep(
    const float* __restrict__ emb, const float* __restrict__ W,
    _Float16* __restrict__ e2, _Float16* __restrict__ w2) {
  const int row = blockIdx.x, tid = threadIdx.x;
  if (row < TP_) {
    for (int j = tid; j < H_; j += 256) {
      float v = (row < T_) ? emb[(size_t)row * H_ + j] : 0.f;
      e2[((size_t)(j >> 3) * TP_ + row) * 8 + (j & 7)] = (_Float16)v;
    }
  } else {
    const int c = row - TP_;
    for (int j = tid; j < H_; j += 256) {
      float v = (c < C_) ? W[(size_t)c * H_ + j] : 0.f;
      w2[((size_t)(j >> 3) * TP_ + c) * 8 + (j & 7)] = (_Float16)v;
    }
  }
}

// ---------------------------------------------------------------------------
// K12: fused scores + G GEMMs with SWAPPED operand roles.
//   A = emb/W fragments (L2-resident, k-major-chunk layout),
//   B = fmap/origin rows (fp32 float4 streams, cvt to fp16).
// D[m][n] comes out as scores[t][l] / G[c][l] -> outputs are written DIRECTLY
// in the transposed layout k3 wants: scT[b][t][1024], GT[b][c][1024].
// Two independent HBM streams per wave (4x1KB loads/k-step) for latency
// hiding. Grid 1024 (= B x 16 slabs of 64 l), block 256, wave = 16 l's.
// Also emits per-slab softmax stats part[1024][112][2] (M, S).
// ---------------------------------------------------------------------------
__global__ __launch_bounds__(256, 4) void k12_fused(
    const float* __restrict__ fmap, const float* __restrict__ origin,
    const _Float16* __restrict__ e2, const _Float16* __restrict__ w2,
    _Float16* __restrict__ scT, _Float16* __restrict__ GT,
    float* __restrict__ part) {
  __shared__ float red_m[4][TP_];
  __shared__ float red_s[4][TP_];
  __shared__ float sMb[TP_];
  const int tid = threadIdx.x;
  const int wave = tid >> 6, lane = tid & 63;
  const int quad = lane >> 4, cc = lane & 15;
  const int b = blockIdx.x >> 4;
  const int lb = (blockIdx.x & 15) * 64 + wave * 16 + cc;  // l within batch

  f32x4 accS[7], accG[7];
#pragma unroll
  for (int i = 0; i < 7; ++i) {
    accS[i] = (f32x4){0.f, 0.f, 0.f, 0.f};
    accG[i] = (f32x4){0.f, 0.f, 0.f, 0.f};
  }

  const float* fp = fmap   + ((size_t)b * L_ + lb) * H_ + quad * 8;
  const float* op = origin + ((size_t)b * L_ + lb) * H_ + quad * 8;
  const _Float16* ep = e2 + (size_t)(quad * TP_ + cc) * 8;
  const _Float16* wp = w2 + (size_t)(quad * TP_ + cc) * 8;

#pragma unroll 2
  for (int k = 0; k < H_; k += 32) {
    float4 x0 = *(const float4*)(fp + k);
    float4 x1 = *(const float4*)(fp + k + 4);
    float4 y0 = *(const float4*)(op + k);
    float4 y1 = *(const float4*)(op + k + 4);
    const _Float16* ek = ep + (size_t)(k >> 3) * (TP_ * 8);
    const _Float16* wk = wp + (size_t)(k >> 3) * (TP_ * 8);
    h8 bf, bo;
    bf[0] = (_Float16)x0.x; bf[1] = (_Float16)x0.y;
    bf[2] = (_Float16)x0.z; bf[3] = (_Float16)x0.w;
    bf[4] = (_Float16)x1.x; bf[5] = (_Float16)x1.y;
    bf[6] = (_Float16)x1.z; bf[7] = (_Float16)x1.w;
    bo[0] = (_Float16)y0.x; bo[1] = (_Float16)y0.y;
    bo[2] = (_Float16)y0.z; bo[3] = (_Float16)y0.w;
    bo[4] = (_Float16)y1.x; bo[5] = (_Float16)y1.y;
    bo[6] = (_Float16)y1.z; bo[7] = (_Float16)y1.w;
#pragma unroll
    for (int i = 0; i < 7; ++i) {
      h8 ae = *(const h8*)(ek + i * 128);
      accS[i] = __builtin_amdgcn_mfma_f32_16x16x32_f16(ae, bf, accS[i], 0, 0, 0);
      h8 aw = *(const h8*)(wk + i * 128);
      accG[i] = __builtin_amdgcn_mfma_f32_16x16x32_f16(aw, bo, accG[i], 0, 0, 0);
    }
  }

  // Wave-partial softmax stats per t over this wave's 16 l's (the cc lanes).
  // acc[i][r] = scores[t = i*16+quad*4+r][l = lb]; reduce across cc via
  // 16-lane-group butterflies (d < 16 stays within the quad group).
#pragma unroll
  for (int i = 0; i < 7; ++i) {
#pragma unroll
    for (int r = 0; r < 4; ++r) {
      float m = accS[i][r];
#pragma unroll
      for (int d = 1; d < 16; d <<= 1) m = fmaxf(m, __shfl_xor(m, d, 64));
      float e = __expf(accS[i][r] - m);
#pragma unroll
      for (int d = 1; d < 16; d <<= 1) e += __shfl_xor(e, d, 64);
      if (cc == 0) {
        red_m[wave][i * 16 + quad * 4 + r] = m;
        red_s[wave][i * 16 + quad * 4 + r] = e;
      }
    }
  }
  __syncthreads();
  if (tid < TP_) {
    float M = red_m[0][tid], S = red_s[0][tid];
#pragma unroll
    for (int w = 1; w < 4; ++w) {
      float om = red_m[w][tid], os = red_s[w][tid];
      float nM = fmaxf(M, om);
      S = S * __expf(M - nM) + os * __expf(om - nM);
      M = nM;
    }
    float* p = part + ((size_t)blockIdx.x * TP_ + tid) * 2;
    p[0] = M; p[1] = S;
    sMb[tid] = M;
  }
  __syncthreads();

  // Outputs land transposed for free: scT[t][l] = fp16(s - M_slab), GT[c][l].
  _Float16* sp = scT + (size_t)b * TP_ * L_ + lb;
  _Float16* gp = GT  + (size_t)b * TP_ * L_ + lb;
#pragma unroll
  for (int i = 0; i < 7; ++i) {
#pragma unroll
    for (int r = 0; r < 4; ++r) {
      const int t = i * 16 + quad * 4 + r;
      sp[(size_t)t * L_] = (_Float16)(accS[i][r] - sMb[t]);
      gp[(size_t)t * L_] = (_Float16)accG[i][r];
    }
  }
}

// ---------------------------------------------------------------------------
// K3: fused softmax + out[b][t][c] = sum_l P[l][t] * G[l][c] + bias[c].
// Both operands now k-major (scT/GT) -> every load is a 16B h8; the exp is
// applied once per sc element on the A-fragment.
// Grid 896 (= B x 7 t-tiles x 2 c-groups), block 512 (8 waves, split-K 8x128),
// cross-wave reduce through LDS.
// ---------------------------------------------------------------------------
__global__ __launch_bounds__(512) void k3_out(
    const _Float16* __restrict__ scT, const _Float16* __restrict__ GT,
    const float* __restrict__ part, const float* __restrict__ bias,
    float* __restrict__ out) {
  __shared__ float sAdj[16][16];   // [slab][t_local]
  __shared__ float sInv[16];
  __shared__ f32x4 sred[8][4][64]; // 32 KB cross-wave reduce
  const int bid = blockIdx.x;
  const int b = bid / 14;
  const int rem = bid % 14;
  const int mt = rem >> 1;              // t-tile 0..6
  const int ng = rem & 1;               // c-group: 0 -> tiles 0..3, 1 -> 4..6
  const int NT = ng ? 3 : 4;
  const int ncol0 = ng * 64;
  const int tid = threadIdx.x;
  const int w = tid >> 6, lane = tid & 63;
  const int quad = lane >> 4, cc = lane & 15;

  // merge the 16 per-slab stats of this batch for this m-tile's 16 t-columns
  if (tid < 16) {
    const int t = mt * 16 + tid;
    float mM[16];
    float M = -1e30f, S = 0.f;
#pragma unroll
    for (int s = 0; s < 16; ++s) {
      const float* p = part + ((size_t)(b * 16 + s) * TP_ + t) * 2;
      float om = p[0], os = p[1];
      mM[s] = om;
      float nM = fmaxf(M, om);
      S = S * __expf(M - nM) + os * __expf(om - nM);
      M = nM;
    }
    sInv[tid] = 1.f / S;
#pragma unroll
    for (int s = 0; s < 16; ++s) sAdj[s][tid] = mM[s] - M;
  }
  __syncthreads();

  f32x4 acc[4];
#pragma unroll
  for (int i = 0; i < 4; ++i) acc[i] = (f32x4){0.f, 0.f, 0.f, 0.f};

  const float inv = sInv[cc];
  const _Float16* ap = scT + ((size_t)(b * TP_ + mt * 16 + cc)) * L_ + quad * 8;
  const _Float16* gp = GT  + ((size_t)(b * TP_ + ncol0 + cc)) * L_ + quad * 8;
  const int kbase = w * 128;
#pragma unroll
  for (int l0 = kbase; l0 < kbase + 128; l0 += 32) {
    const float adj = sAdj[(l0 + quad * 8) >> 6][cc];  // 8 l's stay in 1 slab
    h8 v = *(const h8*)(ap + l0);
    h8 a;
#pragma unroll
    for (int j = 0; j < 8; ++j)
      a[j] = (_Float16)(__expf((float)v[j] + adj) * inv);
#pragma unroll
    for (int nt = 0; nt < 4; ++nt) {
      if (nt < NT) {
        h8 bf = *(const h8*)(gp + (size_t)(nt * 16) * L_ + l0);
        acc[nt] = __builtin_amdgcn_mfma_f32_16x16x32_f16(a, bf, acc[nt], 0, 0, 0);
      }
    }
  }

#pragma unroll
  for (int nt = 0; nt < 4; ++nt)
    if (nt < NT) sred[w][nt][lane] = acc[nt];
  __syncthreads();

  if (w < NT) {
    f32x4 s = sred[0][w][lane];
#pragma unroll
    for (int ww = 1; ww < 8; ++ww) s += sred[ww][w][lane];
    const int c = ncol0 + w * 16 + cc;
    if (c < C_) {
      const float bv = bias[c];
#pragma unroll
      for (int r = 0; r < 4; ++r) {
        const int t = mt * 16 + quad * 4 + r;
        if (t < T_) out[((size_t)b * T_ + t) * C_ + c] = s[r] + bv;
      }
    }
  }
}

// ---------------------------------------------------------------------------
extern "C" void kernel_launch(void* const* d_in, const int* in_sizes, int n_in,
                              void* d_out, int out_size, void* d_ws, size_t ws_size,
                              hipStream_t stream) {
  const float* fmap   = (const float*)d_in[0];  // [B,L,H] fp32
  const float* origin = (const float*)d_in[1];  // [B,L,H] fp32
  const float* emb    = (const float*)d_in[2];  // [T,H]   fp32
  const float* W      = (const float*)d_in[3];  // [C,H]   fp32
  const float* bias   = (const float*)d_in[4];  // [C]     fp32
  float* out = (float*)d_out;                   // [B,T,C] fp32

  char* ws = (char*)d_ws;
  // e2   f16 [64][112][8]      :    114,688 B @ 0
  // w2   f16 [64][112][8]      :    114,688 B @ 114,688
  // scT  f16 [64][112][1024]   : 14,680,064 B @ 229,376
  // part f32 [1024][112][2]    :    917,504 B @ 14,909,440
  // GT   f16 [64][112][1024]   : 14,680,064 B @ 15,826,944   (end 30.5 MB)
  _Float16* e2   = (_Float16*)(ws);
  _Float16* w2   = (_Float16*)(ws + 114688);
  _Float16* scT  = (_Float16*)(ws + 229376);
  float*    part = (float*)   (ws + 14909440);
  _Float16* GT   = (_Float16*)(ws + 15826944);

  hipLaunchKernelGGL(k0_prep,   dim3(224),  dim3(256), 0, stream, emb, W, e2, w2);
  hipLaunchKernelGGL(k12_fused, dim3(1024), dim3(256), 0, stream,
                     fmap, origin, e2, w2, scT, GT, part);
  hipLaunchKernelGGL(k3_out,    dim3(896),  dim3(512), 0, stream,
                     scT, GT, part, bias, out);
}

// Round 4
// 336.888 us; speedup vs baseline: 1.1335x; 1.0616x over previous
//
#include <hip/hip_runtime.h>

// Problem constants
#define B_   64
#define L_   1024
#define H_   512
#define T_   100
#define C_   97
#define TP_  112   // T (and C) padded to 7*16

typedef _Float16 h8 __attribute__((ext_vector_type(8)));   // 8 fp16 (4 VGPRs)
typedef __attribute__((ext_vector_type(4))) float f32x4;   // MFMA C/D

// ---------------------------------------------------------------------------
// k0: prep. pos_emb / W_gen fp32 -> fp16 in k-major-chunk layout
// E2[k/8][112][8]: element (t, k) at ((k>>3)*112 + t)*8 + (k&7).
// Rows t>=100 (emb) / c>=97 (W) are zero. Grid 224.
// ---------------------------------------------------------------------------
__global__ __launch_bounds__(256) void k0_prep(
    const float* __restrict__ emb, const float* __restrict__ W,
    _Float16* __restrict__ e2, _Float16* __restrict__ w2) {
  const int row = blockIdx.x, tid = threadIdx.x;
  if (row < TP_) {
    for (int j = tid; j < H_; j += 256) {
      float v = (row < T_) ? emb[(size_t)row * H_ + j] : 0.f;
      e2[((size_t)(j >> 3) * TP_ + row) * 8 + (j & 7)] = (_Float16)v;
    }
  } else {
    const int c = row - TP_;
    for (int j = tid; j < H_; j += 256) {
      float v = (c < C_) ? W[(size_t)c * H_ + j] : 0.f;
      w2[((size_t)(j >> 3) * TP_ + c) * 8 + (j & 7)] = (_Float16)v;
    }
  }
}

// ---------------------------------------------------------------------------
// K12: fused scores + G GEMMs, swapped operand roles, SOFTWARE-PIPELINED.
//   A = emb/W fragments (L2-resident, k-major-chunk layout),
//   B = fmap/origin rows (fp32 float4 streams, cvt to fp16).
// Register schedule (fits 128-VGPR cap at 16 waves/CU):
//   - depth-1 prefetch of the 4 stream float4s (issued for k+32 while
//     computing k),
//   - fragment loads batch-issued 7 at a time (e-batch -> 7 MFMA,
//     w-batch -> 7 MFMA) so only 28 frag VGPRs are live,
//   - #pragma unroll 1 so the compiler cannot re-inflate the body past
//     the register budget (the round-2 serialization cause).
// Grid 1024 (= B x 16 slabs of 64 l), block 256, wave = 16 l's.
// Outputs transposed for free: scT[b][t][1024], GT[b][c][1024]; per-slab
// softmax stats in part[1024][112][2].
// ---------------------------------------------------------------------------
__global__ __launch_bounds__(256, 4) void k12_fused(
    const float* __restrict__ fmap, const float* __restrict__ origin,
    const _Float16* __restrict__ e2, const _Float16* __restrict__ w2,
    _Float16* __restrict__ scT, _Float16* __restrict__ GT,
    float* __restrict__ part) {
  __shared__ float red_m[4][TP_];
  __shared__ float red_s[4][TP_];
  __shared__ float sMb[TP_];
  const int tid = threadIdx.x;
  const int wave = tid >> 6, lane = tid & 63;
  const int quad = lane >> 4, cc = lane & 15;
  const int b = blockIdx.x >> 4;
  const int lb = (blockIdx.x & 15) * 64 + wave * 16 + cc;  // l within batch

  f32x4 accS[7], accG[7];
#pragma unroll
  for (int i = 0; i < 7; ++i) {
    accS[i] = (f32x4){0.f, 0.f, 0.f, 0.f};
    accG[i] = (f32x4){0.f, 0.f, 0.f, 0.f};
  }

  const float* fp = fmap   + ((size_t)b * L_ + lb) * H_ + quad * 8;
  const float* op = origin + ((size_t)b * L_ + lb) * H_ + quad * 8;
  const _Float16* ep = e2 + (size_t)(quad * TP_ + cc) * 8;
  const _Float16* wp = w2 + (size_t)(quad * TP_ + cc) * 8;

  // prologue: issue stream loads for k = 0
  float4 nx0 = *(const float4*)(fp);
  float4 nx1 = *(const float4*)(fp + 4);
  float4 ny0 = *(const float4*)(op);
  float4 ny1 = *(const float4*)(op + 4);

#pragma unroll 1
  for (int k = 0; k < H_; k += 32) {
    // convert current stream values (waits on loads issued last iteration)
    h8 bf, bo;
    bf[0] = (_Float16)nx0.x; bf[1] = (_Float16)nx0.y;
    bf[2] = (_Float16)nx0.z; bf[3] = (_Float16)nx0.w;
    bf[4] = (_Float16)nx1.x; bf[5] = (_Float16)nx1.y;
    bf[6] = (_Float16)nx1.z; bf[7] = (_Float16)nx1.w;
    bo[0] = (_Float16)ny0.x; bo[1] = (_Float16)ny0.y;
    bo[2] = (_Float16)ny0.z; bo[3] = (_Float16)ny0.w;
    bo[4] = (_Float16)ny1.x; bo[5] = (_Float16)ny1.y;
    bo[6] = (_Float16)ny1.z; bo[7] = (_Float16)ny1.w;

    // issue next k-step's stream loads (wrap on last iter to stay in-bounds)
    const int kn = (k + 32) & (H_ - 1);
    nx0 = *(const float4*)(fp + kn);
    nx1 = *(const float4*)(fp + kn + 4);
    ny0 = *(const float4*)(op + kn);
    ny1 = *(const float4*)(op + kn + 4);

    // e-fragment batch: 7 loads issued together, then 7 MFMAs
    const _Float16* ek = ep + (size_t)(k >> 3) * (TP_ * 8);
    h8 ae[7];
#pragma unroll
    for (int i = 0; i < 7; ++i) ae[i] = *(const h8*)(ek + i * 128);
#pragma unroll
    for (int i = 0; i < 7; ++i)
      accS[i] = __builtin_amdgcn_mfma_f32_16x16x32_f16(ae[i], bf, accS[i], 0, 0, 0);

    // w-fragment batch (reuses the now-dead ae registers)
    const _Float16* wk = wp + (size_t)(k >> 3) * (TP_ * 8);
    h8 aw[7];
#pragma unroll
    for (int i = 0; i < 7; ++i) aw[i] = *(const h8*)(wk + i * 128);
#pragma unroll
    for (int i = 0; i < 7; ++i)
      accG[i] = __builtin_amdgcn_mfma_f32_16x16x32_f16(aw[i], bo, accG[i], 0, 0, 0);
  }

  // Wave-partial softmax stats per t over this wave's 16 l's (the cc lanes).
#pragma unroll
  for (int i = 0; i < 7; ++i) {
#pragma unroll
    for (int r = 0; r < 4; ++r) {
      float m = accS[i][r];
#pragma unroll
      for (int d = 1; d < 16; d <<= 1) m = fmaxf(m, __shfl_xor(m, d, 64));
      float e = __expf(accS[i][r] - m);
#pragma unroll
      for (int d = 1; d < 16; d <<= 1) e += __shfl_xor(e, d, 64);
      if (cc == 0) {
        red_m[wave][i * 16 + quad * 4 + r] = m;
        red_s[wave][i * 16 + quad * 4 + r] = e;
      }
    }
  }
  __syncthreads();
  if (tid < TP_) {
    float M = red_m[0][tid], S = red_s[0][tid];
#pragma unroll
    for (int w = 1; w < 4; ++w) {
      float om = red_m[w][tid], os = red_s[w][tid];
      float nM = fmaxf(M, om);
      S = S * __expf(M - nM) + os * __expf(om - nM);
      M = nM;
    }
    float* p = part + ((size_t)blockIdx.x * TP_ + tid) * 2;
    p[0] = M; p[1] = S;
    sMb[tid] = M;
  }
  __syncthreads();

  // Outputs land transposed for free: scT[t][l] = fp16(s - M_slab), GT[c][l].
  _Float16* sp = scT + (size_t)b * TP_ * L_ + lb;
  _Float16* gp = GT  + (size_t)b * TP_ * L_ + lb;
#pragma unroll
  for (int i = 0; i < 7; ++i) {
#pragma unroll
    for (int r = 0; r < 4; ++r) {
      const int t = i * 16 + quad * 4 + r;
      sp[(size_t)t * L_] = (_Float16)(accS[i][r] - sMb[t]);
      gp[(size_t)t * L_] = (_Float16)accG[i][r];
    }
  }
}

// ---------------------------------------------------------------------------
// K3: fused softmax + out[b][t][c] = sum_l P[l][t] * G[l][c] + bias[c].
// Both operands k-major (scT/GT) -> every load is a 16B h8; exp applied once
// per sc element on the A-fragment. Grid 896 (= B x 7 t-tiles x 2 c-groups),
// block 512 (8 waves, split-K 8x128), cross-wave reduce through LDS.
// ---------------------------------------------------------------------------
__global__ __launch_bounds__(512) void k3_out(
    const _Float16* __restrict__ scT, const _Float16* __restrict__ GT,
    const float* __restrict__ part, const float* __restrict__ bias,
    float* __restrict__ out) {
  __shared__ float sAdj[16][16];   // [slab][t_local]
  __shared__ float sInv[16];
  __shared__ f32x4 sred[8][4][64]; // 32 KB cross-wave reduce
  const int bid = blockIdx.x;
  const int b = bid / 14;
  const int rem = bid % 14;
  const int mt = rem >> 1;              // t-tile 0..6
  const int ng = rem & 1;               // c-group: 0 -> tiles 0..3, 1 -> 4..6
  const int NT = ng ? 3 : 4;
  const int ncol0 = ng * 64;
  const int tid = threadIdx.x;
  const int w = tid >> 6, lane = tid & 63;
  const int quad = lane >> 4, cc = lane & 15;

  // merge the 16 per-slab stats of this batch for this m-tile's 16 t-columns
  if (tid < 16) {
    const int t = mt * 16 + tid;
    float mM[16];
    float M = -1e30f, S = 0.f;
#pragma unroll
    for (int s = 0; s < 16; ++s) {
      const float* p = part + ((size_t)(b * 16 + s) * TP_ + t) * 2;
      float om = p[0], os = p[1];
      mM[s] = om;
      float nM = fmaxf(M, om);
      S = S * __expf(M - nM) + os * __expf(om - nM);
      M = nM;
    }
    sInv[tid] = 1.f / S;
#pragma unroll
    for (int s = 0; s < 16; ++s) sAdj[s][tid] = mM[s] - M;
  }
  __syncthreads();

  f32x4 acc[4];
#pragma unroll
  for (int i = 0; i < 4; ++i) acc[i] = (f32x4){0.f, 0.f, 0.f, 0.f};

  const float inv = sInv[cc];
  const _Float16* ap = scT + ((size_t)(b * TP_ + mt * 16 + cc)) * L_ + quad * 8;
  const _Float16* gp = GT  + ((size_t)(b * TP_ + ncol0 + cc)) * L_ + quad * 8;
  const int kbase = w * 128;
#pragma unroll
  for (int l0 = kbase; l0 < kbase + 128; l0 += 32) {
    const float adj = sAdj[(l0 + quad * 8) >> 6][cc];  // 8 l's stay in 1 slab
    h8 v = *(const h8*)(ap + l0);
    h8 a;
#pragma unroll
    for (int j = 0; j < 8; ++j)
      a[j] = (_Float16)(__expf((float)v[j] + adj) * inv);
#pragma unroll
    for (int nt = 0; nt < 4; ++nt) {
      if (nt < NT) {
        h8 bf = *(const h8*)(gp + (size_t)(nt * 16) * L_ + l0);
        acc[nt] = __builtin_amdgcn_mfma_f32_16x16x32_f16(a, bf, acc[nt], 0, 0, 0);
      }
    }
  }

#pragma unroll
  for (int nt = 0; nt < 4; ++nt)
    if (nt < NT) sred[w][nt][lane] = acc[nt];
  __syncthreads();

  if (w < NT) {
    f32x4 s = sred[0][w][lane];
#pragma unroll
    for (int ww = 1; ww < 8; ++ww) s += sred[ww][w][lane];
    const int c = ncol0 + w * 16 + cc;
    if (c < C_) {
      const float bv = bias[c];
#pragma unroll
      for (int r = 0; r < 4; ++r) {
        const int t = mt * 16 + quad * 4 + r;
        if (t < T_) out[((size_t)b * T_ + t) * C_ + c] = s[r] + bv;
      }
    }
  }
}

// ---------------------------------------------------------------------------
extern "C" void kernel_launch(void* const* d_in, const int* in_sizes, int n_in,
                              void* d_out, int out_size, void* d_ws, size_t ws_size,
                              hipStream_t stream) {
  const float* fmap   = (const float*)d_in[0];  // [B,L,H] fp32
  const float* origin = (const float*)d_in[1];  // [B,L,H] fp32
  const float* emb    = (const float*)d_in[2];  // [T,H]   fp32
  const float* W      = (const float*)d_in[3];  // [C,H]   fp32
  const float* bias   = (const float*)d_in[4];  // [C]     fp32
  float* out = (float*)d_out;                   // [B,T,C] fp32

  char* ws = (char*)d_ws;
  // e2   f16 [64][112][8]      :    114,688 B @ 0
  // w2   f16 [64][112][8]      :    114,688 B @ 114,688
  // scT  f16 [64][112][1024]   : 14,680,064 B @ 229,376
  // part f32 [1024][112][2]    :    917,504 B @ 14,909,440
  // GT   f16 [64][112][1024]   : 14,680,064 B @ 15,826,944   (end 30.5 MB)
  _Float16* e2   = (_Float16*)(ws);
  _Float16* w2   = (_Float16*)(ws + 114688);
  _Float16* scT  = (_Float16*)(ws + 229376);
  float*    part = (float*)   (ws + 14909440);
  _Float16* GT   = (_Float16*)(ws + 15826944);

  hipLaunchKernelGGL(k0_prep,   dim3(224),  dim3(256), 0, stream, emb, W, e2, w2);
  hipLaunchKernelGGL(k12_fused, dim3(1024), dim3(256), 0, stream,
                     fmap, origin, e2, w2, scT, GT, part);
  hipLaunchKernelGGL(k3_out,    dim3(896),  dim3(512), 0, stream,
                     scT, GT, part, bias, out);
}

// Round 5
// 336.312 us; speedup vs baseline: 1.1354x; 1.0017x over previous
//
#include <hip/hip_runtime.h>

// Problem constants
#define B_   64
#define L_   1024
#define H_   512
#define T_   100
#define C_   97
#define TP_  112   // T (and C) padded to 7*16

typedef _Float16 h8 __attribute__((ext_vector_type(8)));   // 8 fp16 (4 VGPRs)
typedef __attribute__((ext_vector_type(4))) float f32x4;   // MFMA C/D

// ---------------------------------------------------------------------------
// k0: prep. pos_emb / W_gen fp32 -> fp16 in k-major-chunk layout
// E2[k/8][112][8]: element (t, k) at ((k>>3)*112 + t)*8 + (k&7).
// Rows t>=100 (emb) / c>=97 (W) are zero. Grid 224.
// ---------------------------------------------------------------------------
__global__ __launch_bounds__(256) void k0_prep(
    const float* __restrict__ emb, const float* __restrict__ W,
    _Float16* __restrict__ e2, _Float16* __restrict__ w2) {
  const int row = blockIdx.x, tid = threadIdx.x;
  if (row < TP_) {
    for (int j = tid; j < H_; j += 256) {
      float v = (row < T_) ? emb[(size_t)row * H_ + j] : 0.f;
      e2[((size_t)(j >> 3) * TP_ + row) * 8 + (j & 7)] = (_Float16)v;
    }
  } else {
    const int c = row - TP_;
    for (int j = tid; j < H_; j += 256) {
      float v = (c < C_) ? W[(size_t)c * H_ + j] : 0.f;
      w2[((size_t)(j >> 3) * TP_ + c) * 8 + (j & 7)] = (_Float16)v;
    }
  }
}

// direct global->LDS DMA, 16B per lane (dest = wave-uniform base + lane*16)
__device__ __forceinline__ void gl_lds16(const float* g, float* l) {
  __builtin_amdgcn_global_load_lds(
      (const __attribute__((address_space(1))) unsigned int*)g,
      (__attribute__((address_space(3))) unsigned int*)l, 16, 0, 0);
}

// ---------------------------------------------------------------------------
// K12: fused scores + G GEMMs, swapped operand roles, LDS-STAGED streams.
//   A = emb/W fragments (L2-resident, k-major-chunk layout, direct global),
//   B = fmap/origin rows staged to LDS via global_load_lds (BK=32 fp32,
//       double-buffered; [8 colgroup][64 row][16B] layout = minimal-conflict
//       ds_read_b128; barriers anchor the pipeline so the compiler cannot
//       collapse it — the round-3/4 register-prefetch failure mode).
// Per iter: [frag loads (L2)] -> [stage next tile] -> [ds_read+cvt] ->
// [14 MFMA, waits vmcnt(4) leaving stage in flight] -> __syncthreads (drain).
// Grid 1024 (= B x 16 slabs of 64 l), block 256, wave = 16 l's.
// Outputs transposed for free: scT[b][t][1024], GT[b][c][1024]; per-slab
// softmax stats in part[1024][112][2].
// ---------------------------------------------------------------------------
__global__ __launch_bounds__(256, 3) void k12_fused(
    const float* __restrict__ fmap, const float* __restrict__ origin,
    const _Float16* __restrict__ e2, const _Float16* __restrict__ w2,
    _Float16* __restrict__ scT, _Float16* __restrict__ GT,
    float* __restrict__ part) {
  __shared__ float sF[2][8][64][4];   // 8 KB x 2 buffers (fmap tile)
  __shared__ float sO[2][8][64][4];   // 8 KB x 2 buffers (origin tile)
  __shared__ float red_m[4][TP_];
  __shared__ float red_s[4][TP_];
  __shared__ float sMb[TP_];
  const int tid = threadIdx.x;
  const int wave = tid >> 6, lane = tid & 63;
  const int quad = lane >> 4, cc = lane & 15;
  const int b = blockIdx.x >> 4;
  const int lb0 = (blockIdx.x & 15) * 64;
  const int rr = wave * 16 + cc;          // this lane's local stream row

  f32x4 accS[7], accG[7];
#pragma unroll
  for (int i = 0; i < 7; ++i) {
    accS[i] = (f32x4){0.f, 0.f, 0.f, 0.f};
    accG[i] = (f32x4){0.f, 0.f, 0.f, 0.f};
  }

  // staging: wave w covers colgroups u0=2w, u1=2w+1; lane = row
  const size_t srow = (size_t)(b * L_ + lb0 + lane) * H_;
  const int u0 = wave * 2, u1 = wave * 2 + 1;
  const _Float16* ep = e2 + (size_t)(quad * TP_ + cc) * 8;
  const _Float16* wp = w2 + (size_t)(quad * TP_ + cc) * 8;

  // prologue: stage tile k=0 into buffer 0
  gl_lds16(fmap   + srow + 0 + u0 * 4, &sF[0][u0][0][0]);
  gl_lds16(fmap   + srow + 0 + u1 * 4, &sF[0][u1][0][0]);
  gl_lds16(origin + srow + 0 + u0 * 4, &sO[0][u0][0][0]);
  gl_lds16(origin + srow + 0 + u1 * 4, &sO[0][u1][0][0]);
  __syncthreads();

#pragma unroll 1
  for (int it = 0; it < 16; ++it) {
    const int k = it * 32;
    const int cur = it & 1;

    // A-fragment loads (L2-resident) — issued BEFORE the stage so the
    // MFMAs' vmcnt wait leaves the 4 stage DMAs outstanding.
    const _Float16* ek = ep + (size_t)(k >> 3) * (TP_ * 8);
    const _Float16* wk = wp + (size_t)(k >> 3) * (TP_ * 8);
    h8 ae[7], aw[7];
#pragma unroll
    for (int i = 0; i < 7; ++i) ae[i] = *(const h8*)(ek + i * 128);
#pragma unroll
    for (int i = 0; i < 7; ++i) aw[i] = *(const h8*)(wk + i * 128);

    // stage next k-tile into the other buffer
    if (it < 15) {
      const int kn = k + 32;
      const int nb = cur ^ 1;
      gl_lds16(fmap   + srow + kn + u0 * 4, &sF[nb][u0][0][0]);
      gl_lds16(fmap   + srow + kn + u1 * 4, &sF[nb][u1][0][0]);
      gl_lds16(origin + srow + kn + u0 * 4, &sO[nb][u0][0][0]);
      gl_lds16(origin + srow + kn + u1 * 4, &sO[nb][u1][0][0]);
    }

    // ds_read current tile (2 x b128 per matrix) + fp32->fp16 convert
    float4 x0 = *(const float4*)&sF[cur][2 * quad][rr][0];
    float4 x1 = *(const float4*)&sF[cur][2 * quad + 1][rr][0];
    float4 y0 = *(const float4*)&sO[cur][2 * quad][rr][0];
    float4 y1 = *(const float4*)&sO[cur][2 * quad + 1][rr][0];
    h8 bf, bo;
    bf[0] = (_Float16)x0.x; bf[1] = (_Float16)x0.y;
    bf[2] = (_Float16)x0.z; bf[3] = (_Float16)x0.w;
    bf[4] = (_Float16)x1.x; bf[5] = (_Float16)x1.y;
    bf[6] = (_Float16)x1.z; bf[7] = (_Float16)x1.w;
    bo[0] = (_Float16)y0.x; bo[1] = (_Float16)y0.y;
    bo[2] = (_Float16)y0.z; bo[3] = (_Float16)y0.w;
    bo[4] = (_Float16)y1.x; bo[5] = (_Float16)y1.y;
    bo[6] = (_Float16)y1.z; bo[7] = (_Float16)y1.w;

#pragma unroll
    for (int i = 0; i < 7; ++i)
      accS[i] = __builtin_amdgcn_mfma_f32_16x16x32_f16(ae[i], bf, accS[i], 0, 0, 0);
#pragma unroll
    for (int i = 0; i < 7; ++i)
      accG[i] = __builtin_amdgcn_mfma_f32_16x16x32_f16(aw[i], bo, accG[i], 0, 0, 0);

    __syncthreads();   // drains stage DMAs; protects buffer reuse
  }

  // Wave-partial softmax stats per t over this wave's 16 l's (the cc lanes).
#pragma unroll
  for (int i = 0; i < 7; ++i) {
#pragma unroll
    for (int r = 0; r < 4; ++r) {
      float m = accS[i][r];
#pragma unroll
      for (int d = 1; d < 16; d <<= 1) m = fmaxf(m, __shfl_xor(m, d, 64));
      float e = __expf(accS[i][r] - m);
#pragma unroll
      for (int d = 1; d < 16; d <<= 1) e += __shfl_xor(e, d, 64);
      if (cc == 0) {
        red_m[wave][i * 16 + quad * 4 + r] = m;
        red_s[wave][i * 16 + quad * 4 + r] = e;
      }
    }
  }
  __syncthreads();
  if (tid < TP_) {
    float M = red_m[0][tid], S = red_s[0][tid];
#pragma unroll
    for (int w = 1; w < 4; ++w) {
      float om = red_m[w][tid], os = red_s[w][tid];
      float nM = fmaxf(M, om);
      S = S * __expf(M - nM) + os * __expf(om - nM);
      M = nM;
    }
    float* p = part + ((size_t)blockIdx.x * TP_ + tid) * 2;
    p[0] = M; p[1] = S;
    sMb[tid] = M;
  }
  __syncthreads();

  // Outputs land transposed for free: scT[t][l] = fp16(s - M_slab), GT[c][l].
  const int lb = lb0 + rr;
  _Float16* sp = scT + (size_t)b * TP_ * L_ + lb;
  _Float16* gp = GT  + (size_t)b * TP_ * L_ + lb;
#pragma unroll
  for (int i = 0; i < 7; ++i) {
#pragma unroll
    for (int r = 0; r < 4; ++r) {
      const int t = i * 16 + quad * 4 + r;
      sp[(size_t)t * L_] = (_Float16)(accS[i][r] - sMb[t]);
      gp[(size_t)t * L_] = (_Float16)accG[i][r];
    }
  }
}

// ---------------------------------------------------------------------------
// K3: fused softmax + out[b][t][c] = sum_l P[l][t] * G[l][c] + bias[c].
// Both operands k-major (scT/GT) -> every load is a 16B h8; exp applied once
// per sc element on the A-fragment. Grid 896 (= B x 7 t-tiles x 2 c-groups),
// block 512 (8 waves, split-K 8x128), cross-wave reduce through LDS.
// ---------------------------------------------------------------------------
__global__ __launch_bounds__(512) void k3_out(
    const _Float16* __restrict__ scT, const _Float16* __restrict__ GT,
    const float* __restrict__ part, const float* __restrict__ bias,
    float* __restrict__ out) {
  __shared__ float sAdj[16][16];   // [slab][t_local]
  __shared__ float sInv[16];
  __shared__ f32x4 sred[8][4][64]; // 32 KB cross-wave reduce
  const int bid = blockIdx.x;
  const int b = bid / 14;
  const int rem = bid % 14;
  const int mt = rem >> 1;              // t-tile 0..6
  const int ng = rem & 1;               // c-group: 0 -> tiles 0..3, 1 -> 4..6
  const int NT = ng ? 3 : 4;
  const int ncol0 = ng * 64;
  const int tid = threadIdx.x;
  const int w = tid >> 6, lane = tid & 63;
  const int quad = lane >> 4, cc = lane & 15;

  // merge the 16 per-slab stats of this batch for this m-tile's 16 t-columns
  if (tid < 16) {
    const int t = mt * 16 + tid;
    float mM[16];
    float M = -1e30f, S = 0.f;
#pragma unroll
    for (int s = 0; s < 16; ++s) {
      const float* p = part + ((size_t)(b * 16 + s) * TP_ + t) * 2;
      float om = p[0], os = p[1];
      mM[s] = om;
      float nM = fmaxf(M, om);
      S = S * __expf(M - nM) + os * __expf(om - nM);
      M = nM;
    }
    sInv[tid] = 1.f / S;
#pragma unroll
    for (int s = 0; s < 16; ++s) sAdj[s][tid] = mM[s] - M;
  }
  __syncthreads();

  f32x4 acc[4];
#pragma unroll
  for (int i = 0; i < 4; ++i) acc[i] = (f32x4){0.f, 0.f, 0.f, 0.f};

  const float inv = sInv[cc];
  const _Float16* ap = scT + ((size_t)(b * TP_ + mt * 16 + cc)) * L_ + quad * 8;
  const _Float16* gp = GT  + ((size_t)(b * TP_ + ncol0 + cc)) * L_ + quad * 8;
  const int kbase = w * 128;
#pragma unroll
  for (int l0 = kbase; l0 < kbase + 128; l0 += 32) {
    const float adj = sAdj[(l0 + quad * 8) >> 6][cc];  // 8 l's stay in 1 slab
    h8 v = *(const h8*)(ap + l0);
    h8 a;
#pragma unroll
    for (int j = 0; j < 8; ++j)
      a[j] = (_Float16)(__expf((float)v[j] + adj) * inv);
#pragma unroll
    for (int nt = 0; nt < 4; ++nt) {
      if (nt < NT) {
        h8 bf = *(const h8*)(gp + (size_t)(nt * 16) * L_ + l0);
        acc[nt] = __builtin_amdgcn_mfma_f32_16x16x32_f16(a, bf, acc[nt], 0, 0, 0);
      }
    }
  }

#pragma unroll
  for (int nt = 0; nt < 4; ++nt)
    if (nt < NT) sred[w][nt][lane] = acc[nt];
  __syncthreads();

  if (w < NT) {
    f32x4 s = sred[0][w][lane];
#pragma unroll
    for (int ww = 1; ww < 8; ++ww) s += sred[ww][w][lane];
    const int c = ncol0 + w * 16 + cc;
    if (c < C_) {
      const float bv = bias[c];
#pragma unroll
      for (int r = 0; r < 4; ++r) {
        const int t = mt * 16 + quad * 4 + r;
        if (t < T_) out[((size_t)b * T_ + t) * C_ + c] = s[r] + bv;
      }
    }
  }
}

// ---------------------------------------------------------------------------
extern "C" void kernel_launch(void* const* d_in, const int* in_sizes, int n_in,
                              void* d_out, int out_size, void* d_ws, size_t ws_size,
                              hipStream_t stream) {
  const float* fmap   = (const float*)d_in[0];  // [B,L,H] fp32
  const float* origin = (const float*)d_in[1];  // [B,L,H] fp32
  const float* emb    = (const float*)d_in[2];  // [T,H]   fp32
  const float* W      = (const float*)d_in[3];  // [C,H]   fp32
  const float* bias   = (const float*)d_in[4];  // [C]     fp32
  float* out = (float*)d_out;                   // [B,T,C] fp32

  char* ws = (char*)d_ws;
  // e2   f16 [64][112][8]      :    114,688 B @ 0
  // w2   f16 [64][112][8]      :    114,688 B @ 114,688
  // scT  f16 [64][112][1024]   : 14,680,064 B @ 229,376
  // part f32 [1024][112][2]    :    917,504 B @ 14,909,440
  // GT   f16 [64][112][1024]   : 14,680,064 B @ 15,826,944   (end 30.5 MB)
  _Float16* e2   = (_Float16*)(ws);
  _Float16* w2   = (_Float16*)(ws + 114688);
  _Float16* scT  = (_Float16*)(ws + 229376);
  float*    part = (float*)   (ws + 14909440);
  _Float16* GT   = (_Float16*)(ws + 15826944);

  hipLaunchKernelGGL(k0_prep,   dim3(224),  dim3(256), 0, stream, emb, W, e2, w2);
  hipLaunchKernelGGL(k12_fused, dim3(1024), dim3(256), 0, stream,
                     fmap, origin, e2, w2, scT, GT, part);
  hipLaunchKernelGGL(k3_out,    dim3(896),  dim3(512), 0, stream,
                     scT, GT, part, bias, out);
}